// Round 2
// baseline (2229.190 us; speedup 1.0000x reference)
//
#include <hip/hip_runtime.h>
#include <hip/hip_bf16.h>
#include <math.h>

#define NB 4
#define NN 128
#define NF 128
#define NS 5
#define NT 32
#define NL 2

typedef __hip_bfloat16 bf16;

__device__ __forceinline__ float b2f(const bf16 x) { return __bfloat162float(x); }
__device__ __forceinline__ float silu_f(float x) { return x / (1.0f + expf(-x)); }

#define PI_F 3.14159265358979323846f

// converted-weights region offsets (floats) within d_ws after the flag slot
#define POS_OFF 0
#define GF_OFF  1536
#define WE_OFF  1664
#define BE_OFF  6400
#define WR1_OFF 6528
#define BR1_OFF 6656
#define WR2_OFF 6784
#define WN_OFF  72320
#define C1_OFF  105088
#define C2_OFF  106112
#define C3_OFF  107136
#define M0_OFF  108160
#define M1_OFF  140928
#define G1_OFF  173696
#define G2_OFF  177792
#define WV_OFF  181888
#define CVT_TOTAL 182144

// ---------------------------------------------------------------------------
// detect: decide whether float inputs are bf16 (flag=1) or f32 (flag=0).
// Reads positions (1536 elems) as bf16 = 3072 bytes, safe under either dtype.
// bf16 N(0,1) data: all finite, |x| < ~5. f32 data misread as bf16: low
// halfwords have random exponents -> huge/NaN values with certainty.
// ---------------------------------------------------------------------------
__global__ void detect_kernel(const void* __restrict__ pos_raw,
                              int* __restrict__ flag)
{
  __shared__ int sbad;
  if (threadIdx.x == 0) sbad = 0;
  __syncthreads();
  const bf16* p = (const bf16*)pos_raw;
  int bad = 0;
  for (int i = threadIdx.x; i < NB*NN*3; i += blockDim.x) {
    float v = b2f(p[i]);
    if (!(fabsf(v) <= 1024.0f)) bad = 1;   // NaN fails the comparison too
  }
  if (bad) sbad = 1;
  __syncthreads();
  if (threadIdx.x == 0) *flag = sbad ? 0 : 1;
}

// ---------------------------------------------------------------------------
// convert: materialize all float inputs as f32 into ws (reads per flag dtype)
// ---------------------------------------------------------------------------
__global__ void convert_kernel(
    const void* __restrict__ pos, const void* __restrict__ gf,
    const void* __restrict__ we,  const void* __restrict__ be,
    const void* __restrict__ wr1, const void* __restrict__ br1,
    const void* __restrict__ wr2, const void* __restrict__ wn,
    const void* __restrict__ c1,  const void* __restrict__ c2,
    const void* __restrict__ c3,  const void* __restrict__ m0,
    const void* __restrict__ m1,  const void* __restrict__ g1,
    const void* __restrict__ g2,  const void* __restrict__ wv,
    const int* __restrict__ flag, float* __restrict__ dst)
{
  const int fl = *flag;
  const int stride = gridDim.x * blockDim.x;
  for (int i = blockIdx.x * blockDim.x + threadIdx.x; i < CVT_TOTAL; i += stride) {
    const void* src; int j;
    if      (i < GF_OFF)  { src = pos; j = i - POS_OFF; }
    else if (i < WE_OFF)  { src = gf;  j = i - GF_OFF; }
    else if (i < BE_OFF)  { src = we;  j = i - WE_OFF; }
    else if (i < WR1_OFF) { src = be;  j = i - BE_OFF; }
    else if (i < BR1_OFF) { src = wr1; j = i - WR1_OFF; }
    else if (i < WR2_OFF) { src = br1; j = i - BR1_OFF; }
    else if (i < WN_OFF)  { src = wr2; j = i - WR2_OFF; }
    else if (i < C1_OFF)  { src = wn;  j = i - WN_OFF; }
    else if (i < C2_OFF)  { src = c1;  j = i - C1_OFF; }
    else if (i < C3_OFF)  { src = c2;  j = i - C2_OFF; }
    else if (i < M0_OFF)  { src = c3;  j = i - C3_OFF; }
    else if (i < M1_OFF)  { src = m0;  j = i - M0_OFF; }
    else if (i < G1_OFF)  { src = m1;  j = i - M1_OFF; }
    else if (i < G2_OFF)  { src = g1;  j = i - G1_OFF; }
    else if (i < WV_OFF)  { src = g2;  j = i - G2_OFF; }
    else                  { src = wv;  j = i - WV_OFF; }
    dst[i] = fl ? b2f(((const bf16*)src)[j]) : ((const float*)src)[j];
  }
}

// ---------------------------------------------------------------------------
// prep: pos_cur copy, env from initial lengths, initial scal embed, vec = 0
// (all reads from converted f32 region)
// ---------------------------------------------------------------------------
__global__ void prep_kernel(
    const float* __restrict__ cvt, const int* __restrict__ nfeat,
    float* __restrict__ pos_cur, float* __restrict__ scal,
    float* __restrict__ vec, float* __restrict__ env)
{
  const float* pos0 = cvt + POS_OFF;
  const int n_pos  = NB*NN*3;      // 1536
  const int n_env  = NB*NN*NN;     // 65536
  const int n_scal = NB*NN*NF;     // 65536
  const int n_vec  = NB*NN*3*NF;   // 196608
  const int total  = n_pos + n_env + n_scal + n_vec;
  int stride = gridDim.x * blockDim.x;
  for (int i = blockIdx.x * blockDim.x + threadIdx.x; i < total; i += stride) {
    if (i < n_pos) {
      pos_cur[i] = pos0[i];
    } else if (i < n_pos + n_env) {
      int e = i - n_pos;
      int b = e / (NN*NN); int rem = e % (NN*NN);
      int r = rem / NN, s = rem % NN;
      const float* pr = pos0 + (b*NN + r)*3;
      const float* ps = pos0 + (b*NN + s)*3;
      float vx = pr[0] - ps[0];
      float vy = pr[1] - ps[1];
      float vz = pr[2] - ps[2];
      float lng = sqrtf(vx*vx + vy*vy + vz*vz + 1e-12f);
      env[e] = (lng < 10.0f) ? 0.5f*(cosf(PI_F * lng * 0.1f) + 1.0f) : 0.0f;
    } else if (i < n_pos + n_env + n_scal) {
      int e = i - n_pos - n_env;
      int b = e / (NN*NF); int rem = e % (NN*NF);
      int n = rem / NF, f = rem % NF;
      int sp = nfeat[b*NN + n] - 1;   // 0..4
      float acc = cvt[WE_OFF + sp*NF + f] + cvt[BE_OFF + f];
      #pragma unroll 8
      for (int t = 0; t < NT; ++t)
        acc += cvt[GF_OFF + b*NT + t] * cvt[WE_OFF + (NS + t)*NF + f];
      scal[e] = acc;
    } else {
      vec[i - n_pos - n_env - n_scal] = 0.0f;
    }
  }
}

// ---------------------------------------------------------------------------
// z = scal @ Wnode[layer]
// ---------------------------------------------------------------------------
__global__ void z_kernel(const float* __restrict__ scal,
                         const float* __restrict__ cvt, int layer,
                         float* __restrict__ z)
{
  int bn = blockIdx.x;
  int f  = threadIdx.x;
  __shared__ float srow[NF];
  srow[f] = scal[bn*NF + f];
  __syncthreads();
  const float* W = cvt + WN_OFF + layer*NF*NF;
  float acc = 0.f;
  #pragma unroll 8
  for (int k = 0; k < NF; ++k)
    acc += srow[k] * W[k*NF + f];
  z[bn*NF + f] = acc;
}

// ---------------------------------------------------------------------------
// EDGE: per (b, receiver r, col-half). Only components c=0..3 are live.
// ---------------------------------------------------------------------------
__global__ __launch_bounds__(256, 4)
void edge_kernel(const float* __restrict__ pos_cur,
                 const float* __restrict__ z,
                 const float* __restrict__ vec,
                 const float* __restrict__ env,
                 const float* __restrict__ cvt,
                 int layer, float* __restrict__ Ag)
{
  __shared__ float Wr2s[64][128];
  __shared__ float wr1s[64], br1s[64];
  __shared__ __align__(16) float hid[64][4];
  __shared__ float fst[4][NF];
  __shared__ float ulds[4][3];
  __shared__ float envs[4];

  const int tid  = threadIdx.x;
  const int bidx = blockIdx.x;
  const int b    = bidx >> 8;
  const int r    = (bidx >> 1) & (NN-1);
  const int half = bidx & 1;
  const int p    = tid >> 7;
  const int fo   = tid & 127;

  const float* W2 = cvt + WR2_OFF + layer*64*512 + half*128;
  for (int i = tid; i < 64*128; i += 256) {
    int h = i >> 7, c = i & 127;
    Wr2s[h][c] = W2[h*512 + c];
  }
  if (tid < 64) {
    wr1s[tid] = cvt[WR1_OFF + layer*64 + tid];
    br1s[tid] = cvt[BR1_OFF + layer*64 + tid];
  }

  const float prx = pos_cur[(b*NN + r)*3 + 0];
  const float pry = pos_cur[(b*NN + r)*3 + 1];
  const float prz = pos_cur[(b*NN + r)*3 + 2];

  float a0 = 0.f, a1 = 0.f, a2 = 0.f, a3 = 0.f;
  __syncthreads();

  for (int s0 = 0; s0 < NN; s0 += 4) {
    {
      int si = tid >> 6;
      int h  = tid & 63;
      int s  = s0 + si;
      float vx = prx - pos_cur[(b*NN + s)*3 + 0];
      float vy = pry - pos_cur[(b*NN + s)*3 + 1];
      float vz = prz - pos_cur[(b*NN + s)*3 + 2];
      float lng = sqrtf(vx*vx + vy*vy + vz*vz + 1e-12f);
      hid[h][si] = silu_f(lng * wr1s[h] + br1s[h]);
      if (h == 0) {
        float inv = 1.0f / lng;
        ulds[si][0] = vx * inv;
        ulds[si][1] = vy * inv;
        ulds[si][2] = vz * inv;
        envs[si] = env[(b*NN + r)*NN + s];
      }
    }
    #pragma unroll
    for (int j = 0; j < 2; ++j) {
      int si = p + 2*j;
      int s  = s0 + si;
      float vx = prx - pos_cur[(b*NN + s)*3 + 0];
      float vy = pry - pos_cur[(b*NN + s)*3 + 1];
      float vz = prz - pos_cur[(b*NN + s)*3 + 2];
      float lng = sqrtf(vx*vx + vy*vy + vz*vz + 1e-12f);
      float inv = 1.0f / lng;
      const float* vb = vec + ((size_t)(b*NN + s)*3)*NF + fo;
      fst[si][fo] = z[(b*NN + s)*NF + fo]
                  + vb[0]*(vx*inv) + vb[NF]*(vy*inv) + vb[2*NF]*(vz*inv);
    }
    __syncthreads();

    float rw0 = 0.f, rw1 = 0.f, rw2 = 0.f, rw3 = 0.f;
    const int hbase = p * 32;
    #pragma unroll
    for (int hh = 0; hh < 32; ++hh) {
      int h = hbase + hh;
      float w = Wr2s[h][fo];
      float4 hv = *(const float4*)&hid[h][0];
      rw0 += hv.x * w;
      rw1 += hv.y * w;
      rw2 += hv.z * w;
      rw3 += hv.w * w;
    }
    #pragma unroll
    for (int si = 0; si < 4; ++si) {
      int s = s0 + si;
      float rv = (si == 0) ? rw0 : (si == 1) ? rw1 : (si == 2) ? rw2 : rw3;
      float sc = (s == r) ? 0.f : envs[si] * 0.0625f;
      rv *= sc;
      float fv = fst[si][fo];
      if (half == 0) {
        a0 += rv * fv;
      } else {
        float tmp = rv * fv * 1.7320508075688772f;
        a1 += tmp * ulds[si][0];
        a2 += tmp * ulds[si][1];
        a3 += tmp * ulds[si][2];
      }
    }
    __syncthreads();
  }

  if (p == 1) {
    fst[0][fo] = a0; fst[1][fo] = a1; fst[2][fo] = a2; fst[3][fo] = a3;
  }
  __syncthreads();
  if (p == 0) {
    a0 += fst[0][fo]; a1 += fst[1][fo]; a2 += fst[2][fo]; a3 += fst[3][fo];
    float* Arow = Ag + ((size_t)(b*NN + r)*4)*NF;
    if (half == 0) {
      float nrm = a0*a0;
      float C1 = cvt[C1_OFF + (layer*4 + 0)*NF + fo];
      float C2 = cvt[C2_OFF + (layer*4 + 0)*NF + fo];
      float C3 = cvt[C3_OFF + (layer*4 + 0)*NF + fo];
      float g = 1.0f + C1*nrm + C2*nrm*nrm + C3*nrm*nrm*nrm;
      Arow[0*NF + fo] = a0 * g;
    } else {
      float nrm = a1*a1 + a2*a2 + a3*a3;
      float C1 = cvt[C1_OFF + (layer*4 + 1)*NF + fo];
      float C2 = cvt[C2_OFF + (layer*4 + 1)*NF + fo];
      float C3 = cvt[C3_OFF + (layer*4 + 1)*NF + fo];
      float g = 1.0f + C1*nrm + C2*nrm*nrm + C3*nrm*nrm*nrm;
      Arow[1*NF + fo] = a1 * g;
      Arow[2*NF + fo] = a2 * g;
      Arow[3*NF + fo] = a3 * g;
    }
  }
}

// ---------------------------------------------------------------------------
// NODE: mix GEMMs, gate MLP, mbv reduction, pos update, (last) output store.
// ---------------------------------------------------------------------------
__global__ void node_kernel(const float* __restrict__ Ag,
                            const float* __restrict__ cvt,
                            int layer, int last,
                            float* __restrict__ scal,
                            float* __restrict__ vec,
                            float* __restrict__ pos_cur,
                            const int* __restrict__ flag,
                            void* __restrict__ out)
{
  int bn = blockIdx.x;
  int f  = threadIdx.x;
  __shared__ float Ash[4][NF];
  __shared__ float scs[NF];
  __shared__ float h16[16];
  __shared__ float red[2][4];

  const float* Arow = Ag + (size_t)bn*4*NF;
  #pragma unroll
  for (int c = 0; c < 4; ++c) Ash[c][f] = Arow[c*NF + f];
  __syncthreads();

  const float* M0 = cvt + M0_OFF + layer*NF*NF;
  const float* M1 = cvt + M1_OFF + layer*NF*NF;
  float sn = 0.f, v0 = 0.f, v1 = 0.f, v2 = 0.f;
  #pragma unroll 4
  for (int k = 0; k < NF; ++k) {
    float m0 = M0[k*NF + f];
    float m1 = M1[k*NF + f];
    sn += Ash[0][k] * m0;
    v0 += Ash[1][k] * m1;
    v1 += Ash[2][k] * m1;
    v2 += Ash[3][k] * m1;
  }
  scs[f] = sn;
  __syncthreads();
  if (f < 16) {
    const float* G1 = cvt + G1_OFF + layer*NF*16;
    float acc = 0.f;
    #pragma unroll 8
    for (int k = 0; k < NF; ++k)
      acc += scs[k] * G1[k*16 + f];
    h16[f] = silu_f(acc);
  }
  __syncthreads();
  const float* G2 = cvt + G2_OFF + layer*16*NF;
  float gate = 0.f;
  #pragma unroll
  for (int j = 0; j < 16; ++j)
    gate += h16[j] * G2[j*NF + f];
  float gv = gate * cvt[WV_OFF + layer*NF + f];

  scal[bn*NF + f] = sn;
  vec[((size_t)bn*3 + 0)*NF + f] = v0;
  vec[((size_t)bn*3 + 1)*NF + f] = v1;
  vec[((size_t)bn*3 + 2)*NF + f] = v2;

  float p0 = v0*gv, p1 = v1*gv, p2 = v2*gv;
  #pragma unroll
  for (int off = 32; off > 0; off >>= 1) {
    p0 += __shfl_down(p0, off, 64);
    p1 += __shfl_down(p1, off, 64);
    p2 += __shfl_down(p2, off, 64);
  }
  int wave = f >> 6;
  if ((f & 63) == 0) { red[wave][0] = p0; red[wave][1] = p1; red[wave][2] = p2; }
  __syncthreads();
  if (f == 0) {
    float m0 = red[0][0] + red[1][0];
    float m1 = red[0][1] + red[1][1];
    float m2 = red[0][2] + red[1][2];
    float px = pos_cur[bn*3+0] + m0;
    float py = pos_cur[bn*3+1] + m1;
    float pz = pos_cur[bn*3+2] + m2;
    pos_cur[bn*3+0] = px;
    pos_cur[bn*3+1] = py;
    pos_cur[bn*3+2] = pz;
    if (last) {
      float ox = px - cvt[POS_OFF + bn*3+0];
      float oy = py - cvt[POS_OFF + bn*3+1];
      float oz = pz - cvt[POS_OFF + bn*3+2];
      if (*flag) {
        bf16* o = (bf16*)out;
        o[bn*3+0] = __float2bfloat16(ox);
        o[bn*3+1] = __float2bfloat16(oy);
        o[bn*3+2] = __float2bfloat16(oz);
      } else {
        float* o = (float*)out;
        o[bn*3+0] = ox;
        o[bn*3+1] = oy;
        o[bn*3+2] = oz;
      }
    }
  }
}

// ---------------------------------------------------------------------------
extern "C" void kernel_launch(void* const* d_in, const int* in_sizes, int n_in,
                              void* d_out, int out_size, void* d_ws, size_t ws_size,
                              hipStream_t stream)
{
  (void)in_sizes; (void)n_in; (void)out_size; (void)ws_size;
  const int* nfeat = (const int*)d_in[1];

  float* ws      = (float*)d_ws;
  int*   flag    = (int*)ws;                  // 16 floats reserved
  float* cvt     = ws + 16;                   // CVT_TOTAL floats
  float* pos_cur = cvt + CVT_TOTAL;           // 1536
  float* scal    = pos_cur + NB*NN*3;         // 65536
  float* vec     = scal + NB*NN*NF;           // 196608
  float* z       = vec + NB*NN*3*NF;          // 65536
  float* Ag      = z + NB*NN*NF;              // 262144
  float* env     = Ag + NB*NN*4*NF;           // 65536

  detect_kernel<<<1, 256, 0, stream>>>(d_in[0], flag);
  convert_kernel<<<256, 256, 0, stream>>>(
      d_in[0], d_in[2], d_in[3], d_in[4], d_in[5], d_in[6], d_in[7], d_in[8],
      d_in[9], d_in[10], d_in[11], d_in[12], d_in[13], d_in[14], d_in[15],
      d_in[16], flag, cvt);
  prep_kernel<<<512, 256, 0, stream>>>(cvt, nfeat, pos_cur, scal, vec, env);
  for (int i = 0; i < NL; ++i) {
    z_kernel<<<NB*NN, NF, 0, stream>>>(scal, cvt, i, z);
    edge_kernel<<<NB*NN*2, 256, 0, stream>>>(pos_cur, z, vec, env, cvt, i, Ag);
    node_kernel<<<NB*NN, NF, 0, stream>>>(Ag, cvt, i, (i == NL-1) ? 1 : 0,
                                          scal, vec, pos_cur, flag, d_out);
  }
}

// Round 4
// 456.786 us; speedup vs baseline: 4.8802x; 4.8802x over previous
//
#include <hip/hip_runtime.h>
#include <hip/hip_bf16.h>
#include <math.h>

#define NB 4
#define NN 128
#define NF 128
#define NS 5
#define NT 32
#define NL 2

typedef __hip_bfloat16 bf16;

__device__ __forceinline__ float b2f(const bf16 x) { return __bfloat162float(x); }
__device__ __forceinline__ float silu_f(float x) { return x / (1.0f + expf(-x)); }

#define PI_F 3.14159265358979323846f
#define SQRT3_F 1.7320508075688772f

// converted-weights region offsets (floats) within d_ws after the flag slot
#define POS_OFF 0
#define GF_OFF  1536
#define WE_OFF  1664
#define BE_OFF  6400
#define WR1_OFF 6528
#define BR1_OFF 6656
#define WR2_OFF 6784
#define WN_OFF  72320
#define C1_OFF  105088
#define C2_OFF  106112
#define C3_OFF  107136
#define M0_OFF  108160
#define M1_OFF  140928
#define G1_OFF  173696
#define G2_OFF  177792
#define WV_OFF  181888
#define CVT_TOTAL 182144

// ---------------------------------------------------------------------------
// detect: bf16 (flag=1) vs f32 (flag=0) float inputs
// ---------------------------------------------------------------------------
__global__ void detect_kernel(const void* __restrict__ pos_raw,
                              int* __restrict__ flag)
{
  __shared__ int sbad;
  if (threadIdx.x == 0) sbad = 0;
  __syncthreads();
  const bf16* p = (const bf16*)pos_raw;
  int bad = 0;
  for (int i = threadIdx.x; i < NB*NN*3; i += blockDim.x) {
    float v = b2f(p[i]);
    if (!(fabsf(v) <= 1024.0f)) bad = 1;
  }
  if (bad) sbad = 1;
  __syncthreads();
  if (threadIdx.x == 0) *flag = sbad ? 0 : 1;
}

// ---------------------------------------------------------------------------
// convert: materialize all float inputs as f32 into ws
// ---------------------------------------------------------------------------
__global__ void convert_kernel(
    const void* __restrict__ pos, const void* __restrict__ gf,
    const void* __restrict__ we,  const void* __restrict__ be,
    const void* __restrict__ wr1, const void* __restrict__ br1,
    const void* __restrict__ wr2, const void* __restrict__ wn,
    const void* __restrict__ c1,  const void* __restrict__ c2,
    const void* __restrict__ c3,  const void* __restrict__ m0,
    const void* __restrict__ m1,  const void* __restrict__ g1,
    const void* __restrict__ g2,  const void* __restrict__ wv,
    const int* __restrict__ flag, float* __restrict__ dst)
{
  const int fl = *flag;
  const int stride = gridDim.x * blockDim.x;
  for (int i = blockIdx.x * blockDim.x + threadIdx.x; i < CVT_TOTAL; i += stride) {
    const void* src; int j;
    if      (i < GF_OFF)  { src = pos; j = i - POS_OFF; }
    else if (i < WE_OFF)  { src = gf;  j = i - GF_OFF; }
    else if (i < BE_OFF)  { src = we;  j = i - WE_OFF; }
    else if (i < WR1_OFF) { src = be;  j = i - BE_OFF; }
    else if (i < BR1_OFF) { src = wr1; j = i - WR1_OFF; }
    else if (i < WR2_OFF) { src = br1; j = i - BR1_OFF; }
    else if (i < WN_OFF)  { src = wr2; j = i - WR2_OFF; }
    else if (i < C1_OFF)  { src = wn;  j = i - WN_OFF; }
    else if (i < C2_OFF)  { src = c1;  j = i - C1_OFF; }
    else if (i < C3_OFF)  { src = c2;  j = i - C2_OFF; }
    else if (i < M0_OFF)  { src = c3;  j = i - C3_OFF; }
    else if (i < M1_OFF)  { src = m0;  j = i - M0_OFF; }
    else if (i < G1_OFF)  { src = m1;  j = i - M1_OFF; }
    else if (i < G2_OFF)  { src = g1;  j = i - G1_OFF; }
    else if (i < WV_OFF)  { src = g2;  j = i - G2_OFF; }
    else                  { src = wv;  j = i - WV_OFF; }
    dst[i] = fl ? b2f(((const bf16*)src)[j]) : ((const float*)src)[j];
  }
}

// ---------------------------------------------------------------------------
// prep: pos_cur copy, env from initial lengths, initial scal embed, vec = 0
// ---------------------------------------------------------------------------
__global__ void prep_kernel(
    const float* __restrict__ cvt, const int* __restrict__ nfeat,
    float* __restrict__ pos_cur, float* __restrict__ scal,
    float* __restrict__ vec, float* __restrict__ env)
{
  const float* pos0 = cvt + POS_OFF;
  const int n_pos  = NB*NN*3;
  const int n_env  = NB*NN*NN;
  const int n_scal = NB*NN*NF;
  const int n_vec  = NB*NN*3*NF;
  const int total  = n_pos + n_env + n_scal + n_vec;
  int stride = gridDim.x * blockDim.x;
  for (int i = blockIdx.x * blockDim.x + threadIdx.x; i < total; i += stride) {
    if (i < n_pos) {
      pos_cur[i] = pos0[i];
    } else if (i < n_pos + n_env) {
      int e = i - n_pos;
      int b = e / (NN*NN); int rem = e % (NN*NN);
      int r = rem / NN, s = rem % NN;
      const float* pr = pos0 + (b*NN + r)*3;
      const float* ps = pos0 + (b*NN + s)*3;
      float vx = pr[0] - ps[0];
      float vy = pr[1] - ps[1];
      float vz = pr[2] - ps[2];
      float lng = sqrtf(vx*vx + vy*vy + vz*vz + 1e-12f);
      env[e] = (lng < 10.0f) ? 0.5f*(cosf(PI_F * lng * 0.1f) + 1.0f) : 0.0f;
    } else if (i < n_pos + n_env + n_scal) {
      int e = i - n_pos - n_env;
      int b = e / (NN*NF); int rem = e % (NN*NF);
      int n = rem / NF, f = rem % NF;
      int sp = nfeat[b*NN + n] - 1;
      float acc = cvt[WE_OFF + sp*NF + f] + cvt[BE_OFF + f];
      #pragma unroll 8
      for (int t = 0; t < NT; ++t)
        acc += cvt[GF_OFF + b*NT + t] * cvt[WE_OFF + (NS + t)*NF + f];
      scal[e] = acc;
    } else {
      vec[i - n_pos - n_env - n_scal] = 0.0f;
    }
  }
}

// ---------------------------------------------------------------------------
// z = scal @ Wnode[layer]
// ---------------------------------------------------------------------------
__global__ void z_kernel(const float* __restrict__ scal,
                         const float* __restrict__ cvt, int layer,
                         float* __restrict__ z)
{
  int bn = blockIdx.x;
  int f  = threadIdx.x;
  __shared__ float srow[NF];
  srow[f] = scal[bn*NF + f];
  __syncthreads();
  const float* W = cvt + WN_OFF + layer*NF*NF;
  float acc = 0.f;
  #pragma unroll 8
  for (int k = 0; k < NF; ++k)
    acc += srow[k] * W[k*NF + f];
  z[bn*NF + f] = acc;
}

// ---------------------------------------------------------------------------
// EDGE v2b: 4 receivers per block, grid = NB*32*2 = 256.
//   (v2 bug fixed: posL staging now covers all 384 floats)
// ---------------------------------------------------------------------------
__global__ __launch_bounds__(256, 2)
void edge_kernel(const float* __restrict__ pos_cur,
                 const float* __restrict__ z,
                 const float* __restrict__ vec,
                 const float* __restrict__ env,
                 const float* __restrict__ cvt,
                 int layer, float* __restrict__ Ag)
{
  __shared__ float posL[NN*3];                 // 1.5 KB current positions, batch b
  __shared__ float envL[4][NN];                // 2 KB
  __shared__ float w1L[64], b1L[64];
  __shared__ float zvL[4][4][NF];              // 8 KB [sender][row: z,vx,vy,vz][fo]
  __shared__ __align__(16) float hidL[4][64][4]; // 4 KB [r][h][sender]
  __shared__ __align__(16) float4 uenvL[4][4]; // [r][sender] {ux,uy,uz,env/16}
  __shared__ float combL[16][NF];              // 8 KB epilogue combine

  const int tid  = threadIdx.x;
  const int bidx = blockIdx.x;                 // b*64 + rt*2 + half
  const int b    = bidx >> 6;
  const int rt   = (bidx >> 1) & 31;
  const int half = bidx & 1;
  const int r0   = rt * 4;
  const int p    = tid >> 7;                   // h-half
  const int fo   = tid & 127;

  // ---- prologue staging ----
  for (int i = tid; i < NN*3; i += 256)        // FIX: was `if (tid < NN*3)` (384>256)
    posL[i] = pos_cur[b*NN*3 + i];
  for (int i = tid; i < 4*NN; i += 256) {
    int rr = i >> 7, s = i & 127;
    envL[rr][s] = env[(b*NN + r0 + rr)*NN + s];
  }
  if (tid < 64) {
    w1L[tid] = cvt[WR1_OFF + layer*64 + tid];
    b1L[tid] = cvt[BR1_OFF + layer*64 + tid];
  }
  // Wr2 columns for this (p, half, fo) into registers
  float w[32];
  {
    const float* W2 = cvt + WR2_OFF + layer*64*512 + half*NF + fo;
    #pragma unroll
    for (int hh = 0; hh < 32; ++hh)
      w[hh] = W2[(p*32 + hh)*512];
  }
  float ac[4][4];                              // [c][r] accumulators
  #pragma unroll
  for (int c = 0; c < 4; ++c)
    #pragma unroll
    for (int r = 0; r < 4; ++r) ac[c][r] = 0.f;

  __syncthreads();

  const int rme = tid >> 6;                    // receiver index for hid staging
  const float hrx = posL[(r0 + rme)*3 + 0];
  const float hry = posL[(r0 + rme)*3 + 1];
  const float hrz = posL[(r0 + rme)*3 + 2];
  const int hme = tid & 63;
  const float w1v = w1L[hme], b1v = b1L[hme];

  for (int s0 = 0; s0 < NN; s0 += 4) {
    // ---- stage z/vec rows for 4 senders: 2048 floats, coalesced ----
    #pragma unroll
    for (int j = 0; j < 8; ++j) {
      int i = tid + j*256;
      int s = i >> 9, row = (i >> 7) & 3, c = i & 127;
      int gs = b*NN + s0 + s;
      zvL[s][row][c] = (row == 0) ? z[gs*NF + c]
                                  : vec[((size_t)gs*3 + row - 1)*NF + c];
    }
    // ---- stage radial-hidden: thread (rme, hme) computes 4 senders ----
    {
      float hv[4];
      #pragma unroll
      for (int si = 0; si < 4; ++si) {
        int s = s0 + si;
        float vx = hrx - posL[s*3 + 0];
        float vy = hry - posL[s*3 + 1];
        float vz = hrz - posL[s*3 + 2];
        float lng = sqrtf(vx*vx + vy*vy + vz*vz + 1e-12f);
        hv[si] = silu_f(lng * w1v + b1v);
      }
      *(float4*)&hidL[rme][hme][0] = make_float4(hv[0], hv[1], hv[2], hv[3]);
    }
    // ---- stage u and env weight per (r, sender) ----
    if (tid < 16) {
      int r = tid >> 2, si = tid & 3;
      int s = s0 + si;
      float vx = posL[(r0 + r)*3 + 0] - posL[s*3 + 0];
      float vy = posL[(r0 + r)*3 + 1] - posL[s*3 + 1];
      float vz = posL[(r0 + r)*3 + 2] - posL[s*3 + 2];
      float lng = sqrtf(vx*vx + vy*vy + vz*vz + 1e-12f);
      float inv = 1.0f / lng;
      float envw = (s == r0 + r) ? 0.f : envL[r][s] * 0.0625f;
      uenvL[r][si] = make_float4(vx*inv, vy*inv, vz*inv, envw);
    }
    __syncthreads();

    // ---- rw partial dots over this thread's h-half ----
    float rw[4][4];
    #pragma unroll
    for (int r = 0; r < 4; ++r)
      #pragma unroll
      for (int si = 0; si < 4; ++si) rw[r][si] = 0.f;
    #pragma unroll
    for (int hh = 0; hh < 32; ++hh) {
      float wv = w[hh];
      int h = p*32 + hh;
      #pragma unroll
      for (int r = 0; r < 4; ++r) {
        float4 hv = *(const float4*)&hidL[r][h][0];
        rw[r][0] += hv.x * wv;
        rw[r][1] += hv.y * wv;
        rw[r][2] += hv.z * wv;
        rw[r][3] += hv.w * wv;
      }
    }
    // ---- consume into A accumulators ----
    #pragma unroll
    for (int si = 0; si < 4; ++si) {
      float zz = zvL[si][0][fo];
      float vx = zvL[si][1][fo];
      float vy = zvL[si][2][fo];
      float vz = zvL[si][3][fo];
      #pragma unroll
      for (int r = 0; r < 4; ++r) {
        float4 ue = uenvL[r][si];
        float fv = zz + ue.x*vx + ue.y*vy + ue.z*vz;
        float rv = rw[r][si] * ue.w;
        if (half == 0) {
          ac[0][r] += rv * fv;
        } else {
          float t = rv * fv * SQRT3_F;
          ac[1][r] += t * ue.x;
          ac[2][r] += t * ue.y;
          ac[3][r] += t * ue.z;
        }
      }
    }
    __syncthreads();
  }

  // ---- combine the two h-halves ----
  if (p == 1) {
    #pragma unroll
    for (int c = 0; c < 4; ++c)
      #pragma unroll
      for (int r = 0; r < 4; ++r)
        combL[c*4 + r][fo] = ac[c][r];
  }
  __syncthreads();
  if (p == 0) {
    #pragma unroll
    for (int c = 0; c < 4; ++c)
      #pragma unroll
      for (int r = 0; r < 4; ++r)
        ac[c][r] += combL[c*4 + r][fo];
    if (half == 0) {
      float C1 = cvt[C1_OFF + (layer*4 + 0)*NF + fo];
      float C2 = cvt[C2_OFF + (layer*4 + 0)*NF + fo];
      float C3 = cvt[C3_OFF + (layer*4 + 0)*NF + fo];
      #pragma unroll
      for (int r = 0; r < 4; ++r) {
        float a0 = ac[0][r];
        float nrm = a0*a0;
        float g = 1.0f + C1*nrm + C2*nrm*nrm + C3*nrm*nrm*nrm;
        Ag[((size_t)(b*NN + r0 + r)*4 + 0)*NF + fo] = a0 * g;
      }
    } else {
      float C1 = cvt[C1_OFF + (layer*4 + 1)*NF + fo];
      float C2 = cvt[C2_OFF + (layer*4 + 1)*NF + fo];
      float C3 = cvt[C3_OFF + (layer*4 + 1)*NF + fo];
      #pragma unroll
      for (int r = 0; r < 4; ++r) {
        float a1 = ac[1][r], a2 = ac[2][r], a3 = ac[3][r];
        float nrm = a1*a1 + a2*a2 + a3*a3;
        float g = 1.0f + C1*nrm + C2*nrm*nrm + C3*nrm*nrm*nrm;
        float* Arow = Ag + ((size_t)(b*NN + r0 + r)*4)*NF;
        Arow[1*NF + fo] = a1 * g;
        Arow[2*NF + fo] = a2 * g;
        Arow[3*NF + fo] = a3 * g;
      }
    }
  }
}

// ---------------------------------------------------------------------------
// NODE: mix GEMMs, gate MLP, mbv reduction, pos update, (last) output store.
// ---------------------------------------------------------------------------
__global__ void node_kernel(const float* __restrict__ Ag,
                            const float* __restrict__ cvt,
                            int layer, int last,
                            float* __restrict__ scal,
                            float* __restrict__ vec,
                            float* __restrict__ pos_cur,
                            const int* __restrict__ flag,
                            void* __restrict__ out)
{
  int bn = blockIdx.x;
  int f  = threadIdx.x;
  __shared__ float Ash[4][NF];
  __shared__ float scs[NF];
  __shared__ float h16[16];
  __shared__ float red[2][4];

  const float* Arow = Ag + (size_t)bn*4*NF;
  #pragma unroll
  for (int c = 0; c < 4; ++c) Ash[c][f] = Arow[c*NF + f];
  __syncthreads();

  const float* M0 = cvt + M0_OFF + layer*NF*NF;
  const float* M1 = cvt + M1_OFF + layer*NF*NF;
  float sn = 0.f, v0 = 0.f, v1 = 0.f, v2 = 0.f;
  #pragma unroll 4
  for (int k = 0; k < NF; ++k) {
    float m0 = M0[k*NF + f];
    float m1 = M1[k*NF + f];
    sn += Ash[0][k] * m0;
    v0 += Ash[1][k] * m1;
    v1 += Ash[2][k] * m1;
    v2 += Ash[3][k] * m1;
  }
  scs[f] = sn;
  __syncthreads();
  if (f < 16) {
    const float* G1 = cvt + G1_OFF + layer*NF*16;
    float acc = 0.f;
    #pragma unroll 8
    for (int k = 0; k < NF; ++k)
      acc += scs[k] * G1[k*16 + f];
    h16[f] = silu_f(acc);
  }
  __syncthreads();
  const float* G2 = cvt + G2_OFF + layer*16*NF;
  float gate = 0.f;
  #pragma unroll
  for (int j = 0; j < 16; ++j)
    gate += h16[j] * G2[j*NF + f];
  float gv = gate * cvt[WV_OFF + layer*NF + f];

  scal[bn*NF + f] = sn;
  vec[((size_t)bn*3 + 0)*NF + f] = v0;
  vec[((size_t)bn*3 + 1)*NF + f] = v1;
  vec[((size_t)bn*3 + 2)*NF + f] = v2;

  float p0 = v0*gv, p1 = v1*gv, p2 = v2*gv;
  #pragma unroll
  for (int off = 32; off > 0; off >>= 1) {
    p0 += __shfl_down(p0, off, 64);
    p1 += __shfl_down(p1, off, 64);
    p2 += __shfl_down(p2, off, 64);
  }
  int wave = f >> 6;
  if ((f & 63) == 0) { red[wave][0] = p0; red[wave][1] = p1; red[wave][2] = p2; }
  __syncthreads();
  if (f == 0) {
    float m0 = red[0][0] + red[1][0];
    float m1 = red[0][1] + red[1][1];
    float m2 = red[0][2] + red[1][2];
    float px = pos_cur[bn*3+0] + m0;
    float py = pos_cur[bn*3+1] + m1;
    float pz = pos_cur[bn*3+2] + m2;
    pos_cur[bn*3+0] = px;
    pos_cur[bn*3+1] = py;
    pos_cur[bn*3+2] = pz;
    if (last) {
      float ox = px - cvt[POS_OFF + bn*3+0];
      float oy = py - cvt[POS_OFF + bn*3+1];
      float oz = pz - cvt[POS_OFF + bn*3+2];
      if (*flag) {
        bf16* o = (bf16*)out;
        o[bn*3+0] = __float2bfloat16(ox);
        o[bn*3+1] = __float2bfloat16(oy);
        o[bn*3+2] = __float2bfloat16(oz);
      } else {
        float* o = (float*)out;
        o[bn*3+0] = ox;
        o[bn*3+1] = oy;
        o[bn*3+2] = oz;
      }
    }
  }
}

// ---------------------------------------------------------------------------
extern "C" void kernel_launch(void* const* d_in, const int* in_sizes, int n_in,
                              void* d_out, int out_size, void* d_ws, size_t ws_size,
                              hipStream_t stream)
{
  (void)in_sizes; (void)n_in; (void)out_size; (void)ws_size;
  const int* nfeat = (const int*)d_in[1];

  float* ws      = (float*)d_ws;
  int*   flag    = (int*)ws;                  // 16 floats reserved
  float* cvt     = ws + 16;                   // CVT_TOTAL floats
  float* pos_cur = cvt + CVT_TOTAL;           // 1536
  float* scal    = pos_cur + NB*NN*3;         // 65536
  float* vec     = scal + NB*NN*NF;           // 196608
  float* z       = vec + NB*NN*3*NF;          // 65536
  float* Ag      = z + NB*NN*NF;              // 262144
  float* env     = Ag + NB*NN*4*NF;           // 65536

  detect_kernel<<<1, 256, 0, stream>>>(d_in[0], flag);
  convert_kernel<<<256, 256, 0, stream>>>(
      d_in[0], d_in[2], d_in[3], d_in[4], d_in[5], d_in[6], d_in[7], d_in[8],
      d_in[9], d_in[10], d_in[11], d_in[12], d_in[13], d_in[14], d_in[15],
      d_in[16], flag, cvt);
  prep_kernel<<<512, 256, 0, stream>>>(cvt, nfeat, pos_cur, scal, vec, env);
  for (int i = 0; i < NL; ++i) {
    z_kernel<<<NB*NN, NF, 0, stream>>>(scal, cvt, i, z);
    edge_kernel<<<256, 256, 0, stream>>>(pos_cur, z, vec, env, cvt, i, Ag);
    node_kernel<<<NB*NN, NF, 0, stream>>>(Ag, cvt, i, (i == NL-1) ? 1 : 0,
                                          scal, vec, pos_cur, flag, d_out);
  }
}

// Round 5
// 269.874 us; speedup vs baseline: 8.2601x; 1.6926x over previous
//
#include <hip/hip_runtime.h>
#include <hip/hip_bf16.h>
#include <math.h>

#define NB 4
#define NN 128
#define NF 128
#define NS 5
#define NT 32
#define NL 2

typedef __hip_bfloat16 bf16;

__device__ __forceinline__ float b2f(const bf16 x) { return __bfloat162float(x); }
__device__ __forceinline__ float silu_f(float x) { return x / (1.0f + expf(-x)); }

#define PI_F 3.14159265358979323846f
#define SQRT3_F 1.7320508075688772f

// converted-weights region offsets (floats) within d_ws after the flag slot
#define POS_OFF 0
#define GF_OFF  1536
#define WE_OFF  1664
#define BE_OFF  6400
#define WR1_OFF 6528
#define BR1_OFF 6656
#define WR2_OFF 6784
#define WN_OFF  72320
#define C1_OFF  105088
#define C2_OFF  106112
#define C3_OFF  107136
#define M0_OFF  108160
#define M1_OFF  140928
#define G1_OFF  173696
#define G2_OFF  177792
#define WV_OFF  181888
#define CVT_TOTAL 182144

// ---------------------------------------------------------------------------
// convert (+ fused detect): each block locally decides bf16 vs f32 from the
// positions array, then converts its slice of all float inputs to f32.
// Block 0 persists the flag for node_kernel's output store.
// ---------------------------------------------------------------------------
__global__ void convert_kernel(
    const void* __restrict__ pos, const void* __restrict__ gf,
    const void* __restrict__ we,  const void* __restrict__ be,
    const void* __restrict__ wr1, const void* __restrict__ br1,
    const void* __restrict__ wr2, const void* __restrict__ wn,
    const void* __restrict__ c1,  const void* __restrict__ c2,
    const void* __restrict__ c3,  const void* __restrict__ m0,
    const void* __restrict__ m1,  const void* __restrict__ g1,
    const void* __restrict__ g2,  const void* __restrict__ wv,
    int* __restrict__ flag, float* __restrict__ dst)
{
  __shared__ int sbad;
  const int tid = threadIdx.x;
  if (tid == 0) sbad = 0;
  __syncthreads();
  {
    const bf16* p = (const bf16*)pos;
    int bad = 0;
    for (int i = tid; i < NB*NN*3; i += blockDim.x) {
      float v = b2f(p[i]);
      if (!(fabsf(v) <= 1024.0f)) bad = 1;   // NaN also fails
    }
    if (bad) sbad = 1;
  }
  __syncthreads();
  const int fl = sbad ? 0 : 1;               // 1 = bf16 inputs
  if (blockIdx.x == 0 && tid == 0) *flag = fl;

  const int stride = gridDim.x * blockDim.x;
  for (int i = blockIdx.x * blockDim.x + tid; i < CVT_TOTAL; i += stride) {
    const void* src; int j;
    if      (i < GF_OFF)  { src = pos; j = i - POS_OFF; }
    else if (i < WE_OFF)  { src = gf;  j = i - GF_OFF; }
    else if (i < BE_OFF)  { src = we;  j = i - WE_OFF; }
    else if (i < WR1_OFF) { src = be;  j = i - BE_OFF; }
    else if (i < BR1_OFF) { src = wr1; j = i - WR1_OFF; }
    else if (i < WR2_OFF) { src = br1; j = i - BR1_OFF; }
    else if (i < WN_OFF)  { src = wr2; j = i - WR2_OFF; }
    else if (i < C1_OFF)  { src = wn;  j = i - WN_OFF; }
    else if (i < C2_OFF)  { src = c1;  j = i - C1_OFF; }
    else if (i < C3_OFF)  { src = c2;  j = i - C2_OFF; }
    else if (i < M0_OFF)  { src = c3;  j = i - C3_OFF; }
    else if (i < M1_OFF)  { src = m0;  j = i - M0_OFF; }
    else if (i < G1_OFF)  { src = m1;  j = i - M1_OFF; }
    else if (i < G2_OFF)  { src = g1;  j = i - G1_OFF; }
    else if (i < WV_OFF)  { src = g2;  j = i - G2_OFF; }
    else                  { src = wv;  j = i - WV_OFF; }
    dst[i] = fl ? b2f(((const bf16*)src)[j]) : ((const float*)src)[j];
  }
}

// ---------------------------------------------------------------------------
// prep v2: one block per node (512 x 128). Computes env row, scal row (LDS
// only), z for layer 0, vec=0, pos_cur.
// ---------------------------------------------------------------------------
__global__ void prep_kernel(
    const float* __restrict__ cvt, const int* __restrict__ nfeat,
    float* __restrict__ pos_cur, float* __restrict__ z,
    float* __restrict__ vec, float* __restrict__ env)
{
  const int bn = blockIdx.x;        // b*NN + n
  const int b  = bn >> 7;
  const int n  = bn & 127;
  const int f  = threadIdx.x;       // 0..127
  __shared__ float posB[NN*3];
  __shared__ float scs[NF];

  for (int i = f; i < NN*3; i += 128)
    posB[i] = cvt[POS_OFF + b*NN*3 + i];

  // scal row (kept only in LDS)
  {
    int sp = nfeat[bn] - 1;
    float acc = cvt[WE_OFF + sp*NF + f] + cvt[BE_OFF + f];
    #pragma unroll 8
    for (int t = 0; t < NT; ++t)
      acc += cvt[GF_OFF + b*NT + t] * cvt[WE_OFF + (NS + t)*NF + f];
    scs[f] = acc;
  }
  __syncthreads();

  // env row (from initial positions)
  {
    float px = posB[n*3+0], py = posB[n*3+1], pz = posB[n*3+2];
    int s = f;
    float vx = px - posB[s*3+0];
    float vy = py - posB[s*3+1];
    float vz = pz - posB[s*3+2];
    float lng = sqrtf(vx*vx + vy*vy + vz*vz + 1e-12f);
    env[bn*NN + s] = (lng < 10.0f) ? 0.5f*(cosf(PI_F*lng*0.1f) + 1.0f) : 0.0f;
  }

  // z for layer 0
  {
    const float* W = cvt + WN_OFF;   // layer 0
    float acc = 0.f;
    #pragma unroll 8
    for (int k = 0; k < NF; ++k)
      acc += scs[k] * W[k*NF + f];
    z[bn*NF + f] = acc;
  }

  // vec = 0
  vec[((size_t)bn*3 + 0)*NF + f] = 0.f;
  vec[((size_t)bn*3 + 1)*NF + f] = 0.f;
  vec[((size_t)bn*3 + 2)*NF + f] = 0.f;

  if (f < 3) pos_cur[bn*3 + f] = posB[n*3 + f];
}

// ---------------------------------------------------------------------------
// EDGE v3: grid = NB*32*4 = 512 blocks (b, 4-receiver tile, 32-sender group),
// 256 threads = (p = h-half, fo = column). Both ell0/ell1 Wr2 columns in
// registers (8 FMA per hid ds_read_b128). Raw partial A accumulated into Ag
// via atomicAdd; gate applied in node_kernel.
// ---------------------------------------------------------------------------
__global__ __launch_bounds__(256, 2)
void edge_kernel(const float* __restrict__ pos_cur,
                 const float* __restrict__ z,
                 const float* __restrict__ vec,
                 const float* __restrict__ env,
                 const float* __restrict__ cvt,
                 int layer, float* __restrict__ Ag)
{
  __shared__ float posL[NN*3];                 // 1.5 KB
  __shared__ float envL[4][32];                // 0.5 KB (this sender group)
  __shared__ float w1L[64], b1L[64];
  __shared__ float zvL[4][4][NF];              // 8 KB
  __shared__ __align__(16) float hidL[4][64][4]; // 4 KB
  __shared__ __align__(16) float4 uenvL[4][4];
  __shared__ float combL[16][NF];              // 8 KB

  const int tid  = threadIdx.x;
  const int bidx = blockIdx.x;                 // b*128 + rt*4 + sg
  const int b    = bidx >> 7;
  const int rt   = (bidx >> 2) & 31;
  const int sg   = bidx & 3;
  const int r0   = rt * 4;
  const int sbase= sg * 32;
  const int p    = tid >> 7;
  const int fo   = tid & 127;

  for (int i = tid; i < NN*3; i += 256)
    posL[i] = pos_cur[b*NN*3 + i];
  if (tid < 128) {
    int rr = tid >> 5, j = tid & 31;
    envL[rr][j] = env[(b*NN + r0 + rr)*NN + sbase + j];
  }
  if (tid < 64) {
    w1L[tid] = cvt[WR1_OFF + layer*64 + tid];
    b1L[tid] = cvt[BR1_OFF + layer*64 + tid];
  }
  // Wr2 columns for both halves into registers
  float wA[32], wB[32];
  {
    const float* W2 = cvt + WR2_OFF + layer*64*512;
    #pragma unroll
    for (int hh = 0; hh < 32; ++hh) {
      wA[hh] = W2[(p*32 + hh)*512 + fo];        // ell0 column
      wB[hh] = W2[(p*32 + hh)*512 + 128 + fo];  // ell1 column
    }
  }
  float ac[4][4];
  #pragma unroll
  for (int c = 0; c < 4; ++c)
    #pragma unroll
    for (int r = 0; r < 4; ++r) ac[c][r] = 0.f;

  __syncthreads();

  const int rme = tid >> 6;
  const int hme = tid & 63;
  const float hrx = posL[(r0 + rme)*3 + 0];
  const float hry = posL[(r0 + rme)*3 + 1];
  const float hrz = posL[(r0 + rme)*3 + 2];
  const float w1v = w1L[hme], b1v = b1L[hme];

  for (int c0 = 0; c0 < 32; c0 += 4) {
    // stage z/vec for 4 senders (2048 floats, coalesced)
    #pragma unroll
    for (int j = 0; j < 8; ++j) {
      int i = tid + j*256;
      int s = i >> 9, row = (i >> 7) & 3, c = i & 127;
      int gs = b*NN + sbase + c0 + s;
      zvL[s][row][c] = (row == 0) ? z[gs*NF + c]
                                  : vec[((size_t)gs*3 + row - 1)*NF + c];
    }
    // stage radial-hidden
    {
      float hv[4];
      #pragma unroll
      for (int si = 0; si < 4; ++si) {
        int s = sbase + c0 + si;
        float vx = hrx - posL[s*3 + 0];
        float vy = hry - posL[s*3 + 1];
        float vz = hrz - posL[s*3 + 2];
        float lng = sqrtf(vx*vx + vy*vy + vz*vz + 1e-12f);
        hv[si] = silu_f(lng * w1v + b1v);
      }
      *(float4*)&hidL[rme][hme][0] = make_float4(hv[0], hv[1], hv[2], hv[3]);
    }
    // stage u + env weight per (r, sender)
    if (tid < 16) {
      int r = tid >> 2, si = tid & 3;
      int s = sbase + c0 + si;
      float vx = posL[(r0 + r)*3 + 0] - posL[s*3 + 0];
      float vy = posL[(r0 + r)*3 + 1] - posL[s*3 + 1];
      float vz = posL[(r0 + r)*3 + 2] - posL[s*3 + 2];
      float lng = sqrtf(vx*vx + vy*vy + vz*vz + 1e-12f);
      float inv = 1.0f / lng;
      float envw = (s == r0 + r) ? 0.f : envL[r][c0 + si] * 0.0625f;
      uenvL[r][si] = make_float4(vx*inv, vy*inv, vz*inv, envw);
    }
    __syncthreads();

    // rw partial dots (both column-halves per thread)
    float rwA[4][4], rwB[4][4];
    #pragma unroll
    for (int r = 0; r < 4; ++r)
      #pragma unroll
      for (int si = 0; si < 4; ++si) { rwA[r][si] = 0.f; rwB[r][si] = 0.f; }
    #pragma unroll
    for (int hh = 0; hh < 32; ++hh) {
      float a = wA[hh], bb = wB[hh];
      int h = p*32 + hh;
      #pragma unroll
      for (int r = 0; r < 4; ++r) {
        float4 hv = *(const float4*)&hidL[r][h][0];
        rwA[r][0] += hv.x * a;  rwB[r][0] += hv.x * bb;
        rwA[r][1] += hv.y * a;  rwB[r][1] += hv.y * bb;
        rwA[r][2] += hv.z * a;  rwB[r][2] += hv.z * bb;
        rwA[r][3] += hv.w * a;  rwB[r][3] += hv.w * bb;
      }
    }
    // consume into A accumulators
    #pragma unroll
    for (int si = 0; si < 4; ++si) {
      float zz = zvL[si][0][fo];
      float vx = zvL[si][1][fo];
      float vy = zvL[si][2][fo];
      float vz = zvL[si][3][fo];
      #pragma unroll
      for (int r = 0; r < 4; ++r) {
        float4 ue = uenvL[r][si];
        float fv = zz + ue.x*vx + ue.y*vy + ue.z*vz;
        ac[0][r] += (rwA[r][si] * ue.w) * fv;
        float t = (rwB[r][si] * ue.w) * fv * SQRT3_F;
        ac[1][r] += t * ue.x;
        ac[2][r] += t * ue.y;
        ac[3][r] += t * ue.z;
      }
    }
    __syncthreads();
  }

  // combine h-halves, then atomically accumulate into Ag (raw, ungated)
  if (p == 1) {
    #pragma unroll
    for (int c = 0; c < 4; ++c)
      #pragma unroll
      for (int r = 0; r < 4; ++r)
        combL[c*4 + r][fo] = ac[c][r];
  }
  __syncthreads();
  if (p == 0) {
    #pragma unroll
    for (int r = 0; r < 4; ++r) {
      float* base = Ag + ((size_t)(b*NN + r0 + r)*4)*NF + fo;
      #pragma unroll
      for (int c = 0; c < 4; ++c)
        atomicAdd(base + c*NF, ac[c][r] + combL[c*4 + r][fo]);
    }
  }
}

// ---------------------------------------------------------------------------
// NODE v2: gate, mix GEMMs, z for next layer, gate MLP, mbv, pos update.
// ---------------------------------------------------------------------------
__global__ void node_kernel(const float* __restrict__ Ag,
                            const float* __restrict__ cvt,
                            int layer, int last,
                            float* __restrict__ vec,
                            float* __restrict__ z,
                            float* __restrict__ pos_cur,
                            const int* __restrict__ flag,
                            void* __restrict__ out)
{
  int bn = blockIdx.x;
  int f  = threadIdx.x;   // 0..127
  __shared__ float Ash[4][NF];
  __shared__ float scs[NF];
  __shared__ float h16[16];
  __shared__ float red[2][4];

  // load raw A and apply correlation gate
  {
    const float* Arow = Ag + (size_t)bn*4*NF;
    float a0 = Arow[0*NF + f];
    float a1 = Arow[1*NF + f];
    float a2 = Arow[2*NF + f];
    float a3 = Arow[3*NF + f];
    float n0 = a0*a0;
    float C1 = cvt[C1_OFF + (layer*4 + 0)*NF + f];
    float C2 = cvt[C2_OFF + (layer*4 + 0)*NF + f];
    float C3 = cvt[C3_OFF + (layer*4 + 0)*NF + f];
    float g0 = 1.0f + C1*n0 + C2*n0*n0 + C3*n0*n0*n0;
    float n1 = a1*a1 + a2*a2 + a3*a3;
    float D1 = cvt[C1_OFF + (layer*4 + 1)*NF + f];
    float D2 = cvt[C2_OFF + (layer*4 + 1)*NF + f];
    float D3 = cvt[C3_OFF + (layer*4 + 1)*NF + f];
    float g1 = 1.0f + D1*n1 + D2*n1*n1 + D3*n1*n1*n1;
    Ash[0][f] = a0 * g0;
    Ash[1][f] = a1 * g1;
    Ash[2][f] = a2 * g1;
    Ash[3][f] = a3 * g1;
  }
  __syncthreads();

  const float* M0 = cvt + M0_OFF + layer*NF*NF;
  const float* M1 = cvt + M1_OFF + layer*NF*NF;
  float sn = 0.f, v0 = 0.f, v1 = 0.f, v2 = 0.f;
  #pragma unroll 4
  for (int k = 0; k < NF; ++k) {
    float m0 = M0[k*NF + f];
    float m1 = M1[k*NF + f];
    sn += Ash[0][k] * m0;
    v0 += Ash[1][k] * m1;
    v1 += Ash[2][k] * m1;
    v2 += Ash[3][k] * m1;
  }
  scs[f] = sn;
  __syncthreads();

  // z for next layer
  if (!last) {
    const float* W = cvt + WN_OFF + (layer+1)*NF*NF;
    float acc = 0.f;
    #pragma unroll 8
    for (int k = 0; k < NF; ++k)
      acc += scs[k] * W[k*NF + f];
    z[bn*NF + f] = acc;
  }

  if (f < 16) {
    const float* G1 = cvt + G1_OFF + layer*NF*16;
    float acc = 0.f;
    #pragma unroll 8
    for (int k = 0; k < NF; ++k)
      acc += scs[k] * G1[k*16 + f];
    h16[f] = silu_f(acc);
  }
  __syncthreads();
  const float* G2 = cvt + G2_OFF + layer*16*NF;
  float gate = 0.f;
  #pragma unroll
  for (int j = 0; j < 16; ++j)
    gate += h16[j] * G2[j*NF + f];
  float gv = gate * cvt[WV_OFF + layer*NF + f];

  vec[((size_t)bn*3 + 0)*NF + f] = v0;
  vec[((size_t)bn*3 + 1)*NF + f] = v1;
  vec[((size_t)bn*3 + 2)*NF + f] = v2;

  float p0 = v0*gv, p1 = v1*gv, p2 = v2*gv;
  #pragma unroll
  for (int off = 32; off > 0; off >>= 1) {
    p0 += __shfl_down(p0, off, 64);
    p1 += __shfl_down(p1, off, 64);
    p2 += __shfl_down(p2, off, 64);
  }
  int wave = f >> 6;
  if ((f & 63) == 0) { red[wave][0] = p0; red[wave][1] = p1; red[wave][2] = p2; }
  __syncthreads();
  if (f == 0) {
    float m0 = red[0][0] + red[1][0];
    float m1 = red[0][1] + red[1][1];
    float m2 = red[0][2] + red[1][2];
    float px = pos_cur[bn*3+0] + m0;
    float py = pos_cur[bn*3+1] + m1;
    float pz = pos_cur[bn*3+2] + m2;
    pos_cur[bn*3+0] = px;
    pos_cur[bn*3+1] = py;
    pos_cur[bn*3+2] = pz;
    if (last) {
      float ox = px - cvt[POS_OFF + bn*3+0];
      float oy = py - cvt[POS_OFF + bn*3+1];
      float oz = pz - cvt[POS_OFF + bn*3+2];
      if (*flag) {
        bf16* o = (bf16*)out;
        o[bn*3+0] = __float2bfloat16(ox);
        o[bn*3+1] = __float2bfloat16(oy);
        o[bn*3+2] = __float2bfloat16(oz);
      } else {
        float* o = (float*)out;
        o[bn*3+0] = ox;
        o[bn*3+1] = oy;
        o[bn*3+2] = oz;
      }
    }
  }
}

// ---------------------------------------------------------------------------
extern "C" void kernel_launch(void* const* d_in, const int* in_sizes, int n_in,
                              void* d_out, int out_size, void* d_ws, size_t ws_size,
                              hipStream_t stream)
{
  (void)in_sizes; (void)n_in; (void)out_size; (void)ws_size;
  const int* nfeat = (const int*)d_in[1];

  float* ws      = (float*)d_ws;
  int*   flag    = (int*)ws;                  // 16 floats reserved
  float* cvt     = ws + 16;                   // CVT_TOTAL floats
  float* pos_cur = cvt + CVT_TOTAL;           // 1536
  float* z       = pos_cur + NB*NN*3;         // 65536
  float* vec     = z + NB*NN*NF;              // 196608
  float* Ag      = vec + NB*NN*3*NF;          // 262144
  float* env     = Ag + NB*NN*4*NF;           // 65536

  convert_kernel<<<256, 256, 0, stream>>>(
      d_in[0], d_in[2], d_in[3], d_in[4], d_in[5], d_in[6], d_in[7], d_in[8],
      d_in[9], d_in[10], d_in[11], d_in[12], d_in[13], d_in[14], d_in[15],
      d_in[16], flag, cvt);
  prep_kernel<<<NB*NN, NF, 0, stream>>>(cvt, nfeat, pos_cur, z, vec, env);
  for (int i = 0; i < NL; ++i) {
    hipMemsetAsync(Ag, 0, (size_t)NB*NN*4*NF*sizeof(float), stream);
    edge_kernel<<<512, 256, 0, stream>>>(pos_cur, z, vec, env, cvt, i, Ag);
    node_kernel<<<NB*NN, NF, 0, stream>>>(Ag, cvt, i, (i == NL-1) ? 1 : 0,
                                          vec, z, pos_cur, flag, d_out);
  }
}